// Round 7
// baseline (709.425 us; speedup 1.0000x reference)
//
#include <hip/hip_runtime.h>
#include <math.h>

// ---------------------------------------------------------------------------
// GAT 3-layer forward, MI355X. Round 6 (resubmit after GPU acquisition
// timeout; no measurement happened):
//  - Double-buffered prefetch K-loop in gemm_mfma (stage next tile BEFORE
//    compute; ONE barrier per K-step) -- hides global->LDS latency under
//    MFMA, removes half the barrier drains.
//  - sd128 / sd32 fused into GEMM2 / GEMM3 epilogues (per-head column block
//    is fully block-local; in-wave shfl reduce + atomicAdd into s/d).
//  - 4 cvt launches merged into 1.
// ---------------------------------------------------------------------------

#define NEG_ATT 0.2f
#define NEG_ACT 0.01f

typedef __attribute__((ext_vector_type(8))) short bf16x8;
typedef __attribute__((ext_vector_type(8))) unsigned short u16x8;
typedef __attribute__((ext_vector_type(4))) float f32x4;

__device__ __forceinline__ float bf2f(unsigned short u) {
  union { unsigned int i; float f; } c; c.i = ((unsigned int)u) << 16; return c.f;
}
__device__ __forceinline__ unsigned short f2bf(float f) {
  union { float f; unsigned int i; } c; c.f = f;
  unsigned int r = c.i + 0x7FFFu + ((c.i >> 16) & 1u);
  return (unsigned short)(r >> 16);
}

// ---------------------------------------------------------------------------
// f32 -> bf16 bulk convert, 4 segments in one launch (n divisible by 8 each)
// ---------------------------------------------------------------------------
__global__ void cvt4_kernel(const float* __restrict__ i0, unsigned short* o0, int n0,
                            const float* __restrict__ i1, unsigned short* o1, int n1,
                            const float* __restrict__ i2, unsigned short* o2, int n2,
                            const float* __restrict__ i3, unsigned short* o3, int n3) {
  int i = blockIdx.x * 256 + threadIdx.x;
  const float* in; unsigned short* out; int idx;
  if (i < n0) { in = i0; out = o0; idx = i; }
  else if (i < n0 + n1) { in = i1; out = o1; idx = i - n0; }
  else if (i < n0 + n1 + n2) { in = i2; out = o2; idx = i - n0 - n1; }
  else if (i < n0 + n1 + n2 + n3) { in = i3; out = o3; idx = i - n0 - n1 - n2; }
  else return;
  float4 v0 = reinterpret_cast<const float4*>(in)[idx * 2];
  float4 v1 = reinterpret_cast<const float4*>(in)[idx * 2 + 1];
  ushort4 q0 = make_ushort4(f2bf(v0.x), f2bf(v0.y), f2bf(v0.z), f2bf(v0.w));
  ushort4 q1 = make_ushort4(f2bf(v1.x), f2bf(v1.y), f2bf(v1.z), f2bf(v1.w));
  reinterpret_cast<ushort4*>(out)[idx * 2] = q0;
  reinterpret_cast<ushort4*>(out)[idx * 2 + 1] = q1;
}

// ---------------------------------------------------------------------------
// Qb[16][256] bf16: rows 0..3 = W1_h^T a_src,h ; rows 4..7 = W1_h^T a_dst,h ;
// rows 8..15 zero (MFMA N-pad).
// ---------------------------------------------------------------------------
__global__ __launch_bounds__(256) void qb_kernel(const float* __restrict__ W1,
    const float* __restrict__ as1, const float* __restrict__ ad1,
    unsigned short* __restrict__ Qb) {
  int r = blockIdx.x;          // output row
  int k = threadIdx.x;         // 0..255
  if (r >= 8) { Qb[r * 256 + k] = 0; return; }
  int h = r & 3;
  const float* av = (r >> 2) ? ad1 : as1;
  float acc = 0.f;
#pragma unroll 8
  for (int c = 0; c < 256; c++)
    acc += W1[((size_t)(h * 256 + c)) * 256 + k] * av[h * 256 + c];
  Qb[r * 256 + k] = f2bf(acc);
}

// ---------------------------------------------------------------------------
// CSR build: histogram -> parallel 3-kernel exclusive scan -> scatter
// ---------------------------------------------------------------------------
__global__ void hist_kernel(const int* __restrict__ edge_dst,
                            int* __restrict__ cnt, int E, int N) {
  int e = blockIdx.x * 256 + threadIdx.x;
  if (e >= E + N) return;
  int dn = (e < E) ? edge_dst[e] : (e - E);   // self-loops appended
  atomicAdd(&cnt[dn], 1);
}

__global__ __launch_bounds__(256) void scan1_kernel(
    const int* __restrict__ cnt, int* __restrict__ bsum, int N) {
  __shared__ int sd_[256];
  int i = blockIdx.x * 256 + threadIdx.x;
  int v = (i < N) ? cnt[i] : 0;
  sd_[threadIdx.x] = v;
  __syncthreads();
#pragma unroll
  for (int off = 128; off; off >>= 1) {
    if (threadIdx.x < off) sd_[threadIdx.x] += sd_[threadIdx.x + off];
    __syncthreads();
  }
  if (threadIdx.x == 0) bsum[blockIdx.x] = sd_[0];
}

__global__ __launch_bounds__(256) void scan2_kernel(
    const int* __restrict__ bsum, int* __restrict__ boff,
    int* __restrict__ row_ptr, int NB, int N) {
  __shared__ int sd_[256];
  int t = threadIdx.x;
  int v = (t < NB) ? bsum[t] : 0;
  sd_[t] = v;
  __syncthreads();
#pragma unroll
  for (int off = 1; off < 256; off <<= 1) {
    int u = (t >= off) ? sd_[t - off] : 0;
    __syncthreads();
    sd_[t] += u;
    __syncthreads();
  }
  if (t < NB) boff[t] = sd_[t] - v;          // exclusive
  if (t == 255) row_ptr[N] = sd_[255];       // total
}

__global__ __launch_bounds__(256) void scan3_kernel(
    const int* __restrict__ cnt, const int* __restrict__ boff,
    int* __restrict__ row_ptr, int* __restrict__ cur, int N) {
  __shared__ int sd_[256];
  int t = threadIdx.x;
  int i = blockIdx.x * 256 + t;
  int v = (i < N) ? cnt[i] : 0;
  sd_[t] = v;
  __syncthreads();
#pragma unroll
  for (int off = 1; off < 256; off <<= 1) {
    int u = (t >= off) ? sd_[t - off] : 0;
    __syncthreads();
    sd_[t] += u;
    __syncthreads();
  }
  if (i < N) {
    int val = boff[blockIdx.x] + sd_[t] - v;
    row_ptr[i] = val;
    cur[i] = val;
  }
}

__global__ void scatter_kernel(const int* __restrict__ edge_src,
                               const int* __restrict__ edge_dst,
                               int* __restrict__ cur,
                               int* __restrict__ src_sorted, int E, int N) {
  int e = blockIdx.x * 256 + threadIdx.x;
  if (e >= E + N) return;
  int sn, dn;
  if (e < E) { sn = edge_src[e]; dn = edge_dst[e]; }
  else       { sn = dn = e - E; }
  int pos = atomicAdd(&cur[dn], 1);
  src_sorted[pos] = sn;
}

// ---------------------------------------------------------------------------
// MFMA bf16 GEMM with double-buffered prefetch + optional fused s/d dots.
// C[m][n] = sum_k A[m][k]*B[n][k] (+ bias[n]); XCD-bijective remap (m204).
// SDMODE: n-block bni covers exactly head bni's C columns; computes
// s[m][bni] = sum_c C_raw[m][c]*a_s[bni*BN+c] (ditto d) via in-wave shfl
// reduce + atomicAdd (s/d must be zero-initialized).
// ---------------------------------------------------------------------------
#define GLOBAL_AS __attribute__((address_space(1)))
#define LDS_AS __attribute__((address_space(3)))

__device__ __forceinline__ void gload_lds16(const void* g, void* l) {
  __builtin_amdgcn_global_load_lds((const GLOBAL_AS unsigned int*)g,
                                   (LDS_AS unsigned int*)l, 16, 0, 0);
}

template <int BM, int BN, int WM, int WN, bool F32OUT, bool SDMODE>
__global__ __launch_bounds__(256) void gemm_mfma(
    const unsigned short* __restrict__ A, const unsigned short* __restrict__ B,
    void* __restrict__ Cv, const float* __restrict__ bias,
    int M, int N, int K, int lda, int ldb, int ldc,
    long long aZ, long long bZ, long long cZ, int biasZ,
    float* __restrict__ sOut, float* __restrict__ dOut,
    const float* __restrict__ a_s, const float* __restrict__ a_d, int H) {
  constexpr int BK = 64;
  constexpr int FM = BM / (WM * 16);
  constexpr int FN = BN / (WN * 16);
  // ---- XCD-bijective remap (m204) ----
  const int flat = blockIdx.x + gridDim.x * (blockIdx.y + gridDim.y * blockIdx.z);
  const int nwg = gridDim.x * gridDim.y * gridDim.z;
  const int xcd = flat & 7, slot = flat >> 3;
  const int q = nwg >> 3, r = nwg & 7;
  const int wgid = (xcd < r ? xcd * (q + 1) : r * (q + 1) + (xcd - r) * q) + slot;
  const int nx = gridDim.x;
  const int per_z = nx * gridDim.y;
  const int bz = wgid / per_z;
  const int rem = wgid - bz * per_z;
  const int bmi = rem / nx;
  const int bni = rem - bmi * nx;

  A += (size_t)bz * aZ;
  B += (size_t)bz * bZ;
  const size_t cbase = (size_t)bz * cZ;
  __shared__ unsigned short As[2][BM * BK];
  __shared__ unsigned short Bs[2][BN * BK];
  const int tid = threadIdx.x;
  const int w = tid >> 6, lane = tid & 63;
  const int wm = w / WN, wn = w % WN;
  const int bm = bmi * BM;
  const int bn = bni * BN;
  const int l15 = lane & 15, l4 = lane >> 4;

  f32x4 acc[FM][FN] = {};

  constexpr int CHA = BM * BK / 8;   // 16B chunks in A tile
  constexpr int CHB = BN * BK / 8;

  auto STAGE = [&](int buf, int k0) {
#pragma unroll
    for (int c0 = 0; c0 < CHA; c0 += 256) {
      int c = c0 + tid;
      if (CHA - c0 >= 256 || tid < CHA - c0) {
        int cl = c ^ ((c >> 3) & 7);
        int row = cl >> 3;
        int kk = (cl & 7) * 8;
        int gr = bm + row; if (gr > M - 1) gr = M - 1;
        gload_lds16(A + (size_t)gr * lda + k0 + kk,
                    As[buf] + (size_t)(c0 + (tid & ~63)) * 8);
      }
    }
#pragma unroll
    for (int c0 = 0; c0 < CHB; c0 += 256) {
      int c = c0 + tid;
      if (CHB - c0 >= 256 || tid < CHB - c0) {
        int cl = c ^ ((c >> 3) & 7);
        int row = cl >> 3;
        int kk = (cl & 7) * 8;
        gload_lds16(B + (size_t)(bn + row) * ldb + k0 + kk,
                    Bs[buf] + (size_t)(c0 + (tid & ~63)) * 8);
      }
    }
  };

  STAGE(0, 0);
  __syncthreads();          // implicit vmcnt(0): buffer 0 ready
  int cur = 0;
  for (int k0 = 0; k0 < K; k0 += BK) {
    if (k0 + BK < K) STAGE(cur ^ 1, k0 + BK);   // prefetch next tile
#pragma unroll
    for (int ks = 0; ks < 2; ks++) {
      bf16x8 af[FM], bfr[FN];
#pragma unroll
      for (int i = 0; i < FM; i++) {
        int row = wm * (FM * 16) + i * 16 + l15;
        int byte = row * (BK * 2) + ks * 64 + l4 * 16;
        byte ^= ((byte >> 7) & 7) << 4;
        af[i] = *reinterpret_cast<const bf16x8*>((const char*)As[cur] + byte);
      }
#pragma unroll
      for (int i = 0; i < FN; i++) {
        int row = wn * (FN * 16) + i * 16 + l15;
        int byte = row * (BK * 2) + ks * 64 + l4 * 16;
        byte ^= ((byte >> 7) & 7) << 4;
        bfr[i] = *reinterpret_cast<const bf16x8*>((const char*)Bs[cur] + byte);
      }
#pragma unroll
      for (int i = 0; i < FM; i++)
#pragma unroll
        for (int jn = 0; jn < FN; jn++)
          acc[i][jn] = __builtin_amdgcn_mfma_f32_16x16x32_bf16(
              af[i], bfr[jn], acc[i][jn], 0, 0, 0);
    }
    __syncthreads();        // drains prefetch (issued ~600cy ago) + read fence
    cur ^= 1;
  }
  // ---- fused s/d dots (from f32 acc, pre-bias) ----
  if constexpr (SDMODE) {
    float aws[FN], awd[FN];
#pragma unroll
    for (int jn = 0; jn < FN; jn++) {
      int c = wn * (FN * 16) + jn * 16 + l15;
      aws[jn] = a_s[bni * BN + c];
      awd[jn] = a_d[bni * BN + c];
    }
#pragma unroll
    for (int i = 0; i < FM; i++) {
#pragma unroll
      for (int r2 = 0; r2 < 4; r2++) {
        float ps = 0.f, pd = 0.f;
#pragma unroll
        for (int jn = 0; jn < FN; jn++) {
          ps = fmaf(acc[i][jn][r2], aws[jn], ps);
          pd = fmaf(acc[i][jn][r2], awd[jn], pd);
        }
#pragma unroll
        for (int o = 1; o < 16; o <<= 1) {
          ps += __shfl_xor(ps, o);
          pd += __shfl_xor(pd, o);
        }
        if (l15 == 0) {
          int m = bm + wm * (FM * 16) + i * 16 + l4 * 4 + r2;
          if (m < M) {
            atomicAdd(&sOut[(size_t)m * H + bni], ps);
            atomicAdd(&dOut[(size_t)m * H + bni], pd);
          }
        }
      }
    }
  }
  // ---- C write: D col = lane&15, row = (lane>>4)*4 + reg (HW-verified) ----
#pragma unroll
  for (int i = 0; i < FM; i++) {
#pragma unroll
    for (int jn = 0; jn < FN; jn++) {
      int col = bn + wn * (FN * 16) + jn * 16 + l15;
      float bv = bias ? bias[biasZ * bz + col] : 0.f;
#pragma unroll
      for (int r2 = 0; r2 < 4; r2++) {
        int m = bm + wm * (FM * 16) + i * 16 + l4 * 4 + r2;
        if (m < M) {
          float val = acc[i][jn][r2] + bv;
          if constexpr (F32OUT)
            ((float*)Cv)[cbase + (size_t)m * ldc + col] = val;
          else
            ((unsigned short*)Cv)[cbase + (size_t)m * ldc + col] = f2bf(val);
        }
      }
    }
  }
}

// ---------------------------------------------------------------------------
// Layer-1 fused softmax + INPUT-space aggregation.
// sd1[n][0..3]=s heads, [4..7]=d heads (f32, from the Qb GEMM).
// One wave per node (4 nodes/block). 3 passes over edges: max, den, acc.
// ---------------------------------------------------------------------------
__global__ __launch_bounds__(256) void aggx_kernel(
    const int* __restrict__ row_ptr, const int* __restrict__ src_sorted,
    const float* __restrict__ sd1, const unsigned short* __restrict__ xb,
    unsigned short* __restrict__ y, int N) {
  __shared__ float alds[4][2][64][4];
  int w = threadIdx.x >> 6, lane = threadIdx.x & 63;
  int n = blockIdx.x * 4 + w;
  if (n >= N) return;
  int beg = row_ptr[n], end = row_ptr[n + 1];
  float4 dv = *reinterpret_cast<const float4*>(sd1 + (size_t)n * 16 + 4);

  auto compE = [&](int t, float e[4]) {
    if (t < end) {
      int sj = src_sorted[t];
      float4 sv = *reinterpret_cast<const float4*>(sd1 + (size_t)sj * 16);
      e[0] = sv.x + dv.x; e[1] = sv.y + dv.y;
      e[2] = sv.z + dv.z; e[3] = sv.w + dv.w;
#pragma unroll
      for (int h = 0; h < 4; h++) e[h] = e[h] > 0.f ? e[h] : NEG_ATT * e[h];
    } else {
      e[0] = e[1] = e[2] = e[3] = -1e30f;
    }
  };

  float mx[4] = {-1e30f, -1e30f, -1e30f, -1e30f};
  for (int cb = beg; cb < end; cb += 64) {
    float e[4]; compE(cb + lane, e);
#pragma unroll
    for (int h = 0; h < 4; h++) {
      float m = e[h];
#pragma unroll
      for (int o = 32; o; o >>= 1) m = fmaxf(m, __shfl_xor(m, o));
      mx[h] = fmaxf(mx[h], m);
    }
  }
  float den[4] = {0.f, 0.f, 0.f, 0.f};
  for (int cb = beg; cb < end; cb += 64) {
    float e[4]; compE(cb + lane, e);
#pragma unroll
    for (int h = 0; h < 4; h++) {
      float p = __expf(e[h] - mx[h]);
#pragma unroll
      for (int o = 32; o; o >>= 1) p += __shfl_xor(p, o);
      den[h] += p;
    }
  }
  float ia[4];
#pragma unroll
  for (int h = 0; h < 4; h++) ia[h] = 1.0f / (den[h] + 1e-16f);

  float acc[4][4] = {};
  for (int cb = beg; cb < end; cb += 64) {
    float e[4]; compE(cb + lane, e);
    int pb = ((cb - beg) >> 6) & 1;
    float4 al;
    al.x = __expf(e[0] - mx[0]) * ia[0];
    al.y = __expf(e[1] - mx[1]) * ia[1];
    al.z = __expf(e[2] - mx[2]) * ia[2];
    al.w = __expf(e[3] - mx[3]) * ia[3];
    *reinterpret_cast<float4*>(alds[w][pb][lane]) = al;
    int cd = end - cb; if (cd > 64) cd = 64;
    for (int j = 0; j < cd; j++) {
      float4 a4 = *reinterpret_cast<const float4*>(alds[w][pb][j]);
      int sj = src_sorted[cb + j];
      ushort4 xv = *reinterpret_cast<const ushort4*>(
          xb + (size_t)sj * 256 + lane * 4);
      float x0 = bf2f(xv.x), x1 = bf2f(xv.y), x2 = bf2f(xv.z), x3 = bf2f(xv.w);
      float ar[4] = {a4.x, a4.y, a4.z, a4.w};
#pragma unroll
      for (int h = 0; h < 4; h++) {
        acc[h][0] = fmaf(ar[h], x0, acc[h][0]);
        acc[h][1] = fmaf(ar[h], x1, acc[h][1]);
        acc[h][2] = fmaf(ar[h], x2, acc[h][2]);
        acc[h][3] = fmaf(ar[h], x3, acc[h][3]);
      }
    }
  }
#pragma unroll
  for (int h = 0; h < 4; h++) {
    ushort4 o = make_ushort4(f2bf(acc[h][0]), f2bf(acc[h][1]),
                             f2bf(acc[h][2]), f2bf(acc[h][3]));
    *reinterpret_cast<ushort4*>(y + (size_t)n * 1024 + h * 256 + lane * 4) = o;
  }
}

// ---------------------------------------------------------------------------
// Layer-2 fused softmax + aggregation + bias + LN(512) + leaky_relu.
// ---------------------------------------------------------------------------
__global__ __launch_bounds__(256) void agg2m_kernel(
    const int* __restrict__ row_ptr, const int* __restrict__ src_sorted,
    const float* __restrict__ s2, const float* __restrict__ d2,
    const unsigned short* __restrict__ h2, const float* __restrict__ bias,
    const float* __restrict__ ln_g, const float* __restrict__ ln_b,
    unsigned short* __restrict__ outb, int N) {
  __shared__ float alds[4][2][64][4];
  int w = threadIdx.x >> 6, lane = threadIdx.x & 63;
  int n = blockIdx.x * 4 + w;
  if (n >= N) return;
  int beg = row_ptr[n], end = row_ptr[n + 1];
  int head = lane >> 4, c0 = lane * 8;
  float4 dv = *reinterpret_cast<const float4*>(d2 + (size_t)n * 4);

  auto compE = [&](int t, float e[4]) {
    if (t < end) {
      int sj = src_sorted[t];
      float4 sv = *reinterpret_cast<const float4*>(s2 + (size_t)sj * 4);
      e[0] = sv.x + dv.x; e[1] = sv.y + dv.y;
      e[2] = sv.z + dv.z; e[3] = sv.w + dv.w;
#pragma unroll
      for (int h = 0; h < 4; h++) e[h] = e[h] > 0.f ? e[h] : NEG_ATT * e[h];
    } else {
      e[0] = e[1] = e[2] = e[3] = -1e30f;
    }
  };

  float mx[4] = {-1e30f, -1e30f, -1e30f, -1e30f};
  for (int cb = beg; cb < end; cb += 64) {
    float e[4]; compE(cb + lane, e);
#pragma unroll
    for (int h = 0; h < 4; h++) {
      float m = e[h];
#pragma unroll
      for (int o = 32; o; o >>= 1) m = fmaxf(m, __shfl_xor(m, o));
      mx[h] = fmaxf(mx[h], m);
    }
  }
  float den[4] = {0.f, 0.f, 0.f, 0.f};
  for (int cb = beg; cb < end; cb += 64) {
    float e[4]; compE(cb + lane, e);
#pragma unroll
    for (int h = 0; h < 4; h++) {
      float p = __expf(e[h] - mx[h]);
#pragma unroll
      for (int o = 32; o; o >>= 1) p += __shfl_xor(p, o);
      den[h] += p;
    }
  }
  float ia[4];
#pragma unroll
  for (int h = 0; h < 4; h++) ia[h] = 1.0f / (den[h] + 1e-16f);

  float acc[8] = {};
  for (int cb = beg; cb < end; cb += 64) {
    float e[4]; compE(cb + lane, e);
    int pb = ((cb - beg) >> 6) & 1;
    float4 al;
    al.x = __expf(e[0] - mx[0]) * ia[0];
    al.y = __expf(e[1] - mx[1]) * ia[1];
    al.z = __expf(e[2] - mx[2]) * ia[2];
    al.w = __expf(e[3] - mx[3]) * ia[3];
    *reinterpret_cast<float4*>(alds[w][pb][lane]) = al;
    int cd = end - cb; if (cd > 64) cd = 64;
    for (int j = 0; j < cd; j++) {
      float a = alds[w][pb][j][head];
      int sj = src_sorted[cb + j];
      u16x8 xv = *reinterpret_cast<const u16x8*>(h2 + (size_t)sj * 512 + c0);
#pragma unroll
      for (int i = 0; i < 8; i++)
        acc[i] = fmaf(a, bf2f(xv[i]), acc[i]);
    }
  }
  float v[8], s1 = 0.f, sq = 0.f;
#pragma unroll
  for (int i = 0; i < 8; i++) {
    v[i] = acc[i] + bias[c0 + i];
    s1 += v[i]; sq += v[i] * v[i];
  }
#pragma unroll
  for (int o = 32; o; o >>= 1) { s1 += __shfl_xor(s1, o); sq += __shfl_xor(sq, o); }
  float mean = s1 * (1.0f / 512.0f);
  float var = sq * (1.0f / 512.0f) - mean * mean;
  float rstd = rsqrtf(var + 1e-5f);
  u16x8 ov;
#pragma unroll
  for (int i = 0; i < 8; i++) {
    float yv = (v[i] - mean) * rstd * ln_g[c0 + i] + ln_b[c0 + i];
    yv = yv > 0.f ? yv : NEG_ACT * yv;
    ov[i] = f2bf(yv);
  }
  *reinterpret_cast<u16x8*>(outb + (size_t)n * 512 + c0) = ov;
}

// ---------------------------------------------------------------------------
// LN(1024) + leaky over z1 -> act1 (bias folded into GEMM epilogue).
// ---------------------------------------------------------------------------
__global__ __launch_bounds__(256) void ln1024_kernel(
    const unsigned short* __restrict__ z, const float* __restrict__ ln_g,
    const float* __restrict__ ln_b, unsigned short* __restrict__ outb, int N) {
  int n = blockIdx.x;
  int tid = threadIdx.x;
  int c0 = tid * 4;
  ushort4 zv = *reinterpret_cast<const ushort4*>(z + (size_t)n * 1024 + c0);
  float v[4] = {bf2f(zv.x), bf2f(zv.y), bf2f(zv.z), bf2f(zv.w)};
  float s1 = v[0] + v[1] + v[2] + v[3];
  float sq = v[0]*v[0] + v[1]*v[1] + v[2]*v[2] + v[3]*v[3];
#pragma unroll
  for (int o = 32; o; o >>= 1) { s1 += __shfl_down(s1, o); sq += __shfl_down(sq, o); }
  __shared__ float r1[4], r2[4];
  int wave = tid >> 6, lane = tid & 63;
  if (lane == 0) { r1[wave] = s1; r2[wave] = sq; }
  __syncthreads();
  float t1 = r1[0] + r1[1] + r1[2] + r1[3];
  float t2 = r2[0] + r2[1] + r2[2] + r2[3];
  float mean = t1 * (1.0f / 1024.0f);
  float var = t2 * (1.0f / 1024.0f) - mean * mean;
  float rstd = rsqrtf(var + 1e-5f);
  ushort4 ov;
  float y0 = (v[0] - mean) * rstd * ln_g[c0 + 0] + ln_b[c0 + 0];
  float y1 = (v[1] - mean) * rstd * ln_g[c0 + 1] + ln_b[c0 + 1];
  float y2 = (v[2] - mean) * rstd * ln_g[c0 + 2] + ln_b[c0 + 2];
  float y3 = (v[3] - mean) * rstd * ln_g[c0 + 3] + ln_b[c0 + 3];
  ov.x = f2bf(y0 > 0.f ? y0 : NEG_ACT * y0);
  ov.y = f2bf(y1 > 0.f ? y1 : NEG_ACT * y1);
  ov.z = f2bf(y2 > 0.f ? y2 : NEG_ACT * y2);
  ov.w = f2bf(y3 > 0.f ? y3 : NEG_ACT * y3);
  *reinterpret_cast<ushort4*>(outb + (size_t)n * 1024 + c0) = ov;
}

// ---------------------------------------------------------------------------
// Layer-3 softmax stats (H=1).
// ---------------------------------------------------------------------------
__global__ void stats_kernel(const int* __restrict__ row_ptr,
    const int* __restrict__ src_sorted, const float* __restrict__ s,
    const float* __restrict__ d, float* __restrict__ p_sorted,
    float* __restrict__ inv_den, int N) {
  int idx = blockIdx.x * blockDim.x + threadIdx.x;
  if (idx >= N) return;
  int n = idx;
  int beg = row_ptr[n], end = row_ptr[n + 1];
  float dn = d[n];
  float mx = -1e30f;
  for (int j = beg; j < end; j++) {
    float v = s[src_sorted[j]] + dn;
    v = v > 0.f ? v : NEG_ATT * v;
    mx = fmaxf(mx, v);
  }
  float den = 0.f;
  for (int j = beg; j < end; j++) {
    float v = s[src_sorted[j]] + dn;
    v = v > 0.f ? v : NEG_ATT * v;
    float p = __expf(v - mx);
    p_sorted[j] = p;
    den += p;
  }
  inv_den[n] = 1.0f / (den + 1e-16f);
}

// ---------------------------------------------------------------------------
// Layer-3 aggregation + bias + LN(32) + log_softmax(32) -> f32 output.
// ---------------------------------------------------------------------------
__global__ __launch_bounds__(256) void final_kernel(
    const int* __restrict__ row_ptr, const int* __restrict__ src_sorted,
    const float* __restrict__ p_sorted, const float* __restrict__ inv_den,
    const unsigned short* __restrict__ h3, const float* __restrict__ b3,
    const float* __restrict__ g3, const float* __restrict__ bb3,
    float* __restrict__ out, int N) {
  int idx = blockIdx.x * 256 + threadIdx.x;
  int n = idx >> 5, c = idx & 31;
  if (n >= N) return;
  int beg = row_ptr[n], end = row_ptr[n + 1];
  float acc = 0.f;
  for (int j = beg; j < end; j++)
    acc = fmaf(p_sorted[j], bf2f(h3[(size_t)src_sorted[j] * 32 + c]), acc);
  float v = acc * inv_den[n] + b3[c];
  float s1 = v, s2 = v * v;
#pragma unroll
  for (int o = 16; o; o >>= 1) { s1 += __shfl_xor(s1, o, 32); s2 += __shfl_xor(s2, o, 32); }
  float mean = s1 * (1.f / 32.f), var = s2 * (1.f / 32.f) - mean * mean;
  float y = (v - mean) * rsqrtf(var + 1e-5f) * g3[c] + bb3[c];
  float mx = y;
#pragma unroll
  for (int o = 16; o; o >>= 1) mx = fmaxf(mx, __shfl_xor(mx, o, 32));
  float ex = __expf(y - mx), se = ex;
#pragma unroll
  for (int o = 16; o; o >>= 1) se += __shfl_xor(se, o, 32);
  out[(size_t)n * 32 + c] = y - mx - __logf(se);
}

// ---------------------------------------------------------------------------
extern "C" void kernel_launch(void* const* d_in, const int* in_sizes, int n_in,
                              void* d_out, int out_size, void* d_ws,
                              size_t ws_size, hipStream_t stream) {
  const float* x   = (const float*)d_in[0];
  const int* esrc  = (const int*)d_in[1];
  const int* edst  = (const int*)d_in[2];
  const float* W1  = (const float*)d_in[3];
  const float* as1 = (const float*)d_in[4];
  const float* ad1 = (const float*)d_in[5];
  const float* b1  = (const float*)d_in[6];
  const float* g1  = (const float*)d_in[7];
  const float* bb1 = (const float*)d_in[8];
  const float* W2  = (const float*)d_in[9];
  const float* as2 = (const float*)d_in[10];
  const float* ad2 = (const float*)d_in[11];
  const float* b2  = (const float*)d_in[12];
  const float* g2  = (const float*)d_in[13];
  const float* bb2 = (const float*)d_in[14];
  const float* W3  = (const float*)d_in[15];
  const float* as3 = (const float*)d_in[16];
  const float* ad3 = (const float*)d_in[17];
  const float* b3  = (const float*)d_in[18];
  const float* g3  = (const float*)d_in[19];
  const float* bb3 = (const float*)d_in[20];
  float* out = (float*)d_out;

  const int Nn = in_sizes[0] / 256;  // 50000
  const int E  = in_sizes[1];        // 400000
  const int Etot = E + Nn;
  const int NB = (Nn + 255) / 256;   // 196 scan blocks (<=256 required)

  char* ws = (char*)d_ws;
  size_t off = 0;
  auto alloc = [&](size_t bytes) -> char* {
    char* p = ws + off;
    off += (bytes + 255) & ~(size_t)255;
    return p;
  };
  // small buffers
  int* cnt        = (int*)alloc((size_t)(Nn + 1) * 4);
  int* cur        = (int*)alloc((size_t)(Nn + 1) * 4);
  int* row_ptr    = (int*)alloc((size_t)(Nn + 1) * 4);
  int* bsum       = (int*)alloc(256 * 4);
  int* boff       = (int*)alloc(256 * 4);
  int* src_sorted = (int*)alloc((size_t)Etot * 4);
  float* sd1   = (float*)alloc((size_t)Nn * 16 * 4);   // s(0..3), d(4..7)
  // contiguous s2(4)/d2(4)/s3(1)/d3(1) -> one zeroing memset
  float* sdbuf = (float*)alloc((size_t)Nn * 10 * 4);
  float* s2 = sdbuf;
  float* d2 = sdbuf + (size_t)Nn * 4;
  float* s3 = sdbuf + (size_t)Nn * 8;
  float* d3 = sdbuf + (size_t)Nn * 9;
  float* invd3 = (float*)alloc((size_t)Nn * 4);
  float* p3    = (float*)alloc((size_t)Etot * 4);
  unsigned short* W1b = (unsigned short*)alloc((size_t)1024 * 256 * 2);
  unsigned short* W2b = (unsigned short*)alloc((size_t)512 * 1024 * 2);
  unsigned short* W3b = (unsigned short*)alloc((size_t)32 * 512 * 2);
  unsigned short* Qb  = (unsigned short*)alloc((size_t)16 * 256 * 2);
  unsigned short* h3  = (unsigned short*)alloc((size_t)Nn * 32 * 2);
  // big regions (102.4 MB each) with lifetime-based overlays:
  //   regionA: y -> act1 -> act2
  //   regionB: xb -> z1 -> h2
  unsigned short* regA = (unsigned short*)alloc((size_t)Nn * 1024 * 2);
  unsigned short* regB = (unsigned short*)alloc((size_t)Nn * 1024 * 2);
  unsigned short* y    = regA;
  unsigned short* act1 = regA;
  unsigned short* act2 = regA;
  unsigned short* xb   = regB;
  unsigned short* z1   = regB;
  unsigned short* h2   = regB;

  const int mb = (Nn + 127) / 128;

  // ---- prep: bf16 conversions (single launch) + Qb ----
  {
    int n0 = Nn * 256 / 8, n1 = 1024 * 256 / 8, n2 = 512 * 1024 / 8, n3 = 32 * 512 / 8;
    int tot = n0 + n1 + n2 + n3;
    cvt4_kernel<<<(tot + 255) / 256, 256, 0, stream>>>(
        x, xb, n0, W1, W1b, n1, W2, W2b, n2, W3, W3b, n3);
  }
  qb_kernel<<<16, 256, 0, stream>>>(W1, as1, ad1, Qb);

  // ---- CSR by dst (parallel scan) + zero s/d accumulators ----
  hipMemsetAsync(cnt, 0, (size_t)(Nn + 1) * 4, stream);
  hipMemsetAsync(sdbuf, 0, (size_t)Nn * 10 * 4, stream);
  int eb = (Etot + 255) / 256;
  hist_kernel<<<eb, 256, 0, stream>>>(edst, cnt, E, Nn);
  scan1_kernel<<<NB, 256, 0, stream>>>(cnt, bsum, Nn);
  scan2_kernel<<<1, 256, 0, stream>>>(bsum, boff, row_ptr, NB, Nn);
  scan3_kernel<<<NB, 256, 0, stream>>>(cnt, boff, row_ptr, cur, Nn);
  scatter_kernel<<<eb, 256, 0, stream>>>(esrc, edst, cur, src_sorted, E, Nn);

  // ---- layer 1 (input-space aggregation) ----
  gemm_mfma<128, 16, 4, 1, true, false><<<dim3(1, mb, 1), 256, 0, stream>>>(
      xb, Qb, sd1, nullptr, Nn, 16, 256, 256, 256, 16, 0, 0, 0, 0,
      nullptr, nullptr, nullptr, nullptr, 0);
  aggx_kernel<<<(Nn + 3) / 4, 256, 0, stream>>>(row_ptr, src_sorted, sd1, xb, y, Nn);
  gemm_mfma<128, 128, 2, 2, false, false><<<dim3(2, mb, 4), 256, 0, stream>>>(
      y, W1b, z1, b1, Nn, 256, 256, 1024, 256, 1024, 256LL, 256LL * 256, 256LL, 256,
      nullptr, nullptr, nullptr, nullptr, 0);
  ln1024_kernel<<<Nn, 256, 0, stream>>>(z1, g1, bb1, act1, Nn);

  // ---- layer 2 (sd fused into GEMM epilogue) ----
  gemm_mfma<128, 128, 2, 2, false, true><<<dim3(4, mb, 1), 256, 0, stream>>>(
      act1, W2b, h2, nullptr, Nn, 512, 1024, 1024, 1024, 512, 0, 0, 0, 0,
      s2, d2, as2, ad2, 4);
  agg2m_kernel<<<(Nn + 3) / 4, 256, 0, stream>>>(row_ptr, src_sorted, s2, d2,
                                                 h2, b2, g2, bb2, act2, Nn);

  // ---- layer 3 (sd fused into GEMM epilogue) ----
  gemm_mfma<128, 32, 4, 1, false, true><<<dim3(1, mb, 1), 256, 0, stream>>>(
      act2, W3b, h3, nullptr, Nn, 32, 512, 512, 512, 32, 0, 0, 0, 0,
      s3, d3, as3, ad3, 1);
  stats_kernel<<<(Nn + 255) / 256, 256, 0, stream>>>(row_ptr, src_sorted,
                                                     s3, d3, p3, invd3, Nn);
  final_kernel<<<(Nn * 32 + 255) / 256, 256, 0, stream>>>(row_ptr, src_sorted,
      p3, invd3, h3, b3, g3, bb3, out, Nn);
}

// Round 9
// 657.991 us; speedup vs baseline: 1.0782x; 1.0782x over previous
//
#include <hip/hip_runtime.h>
#include <math.h>

// ---------------------------------------------------------------------------
// GAT 3-layer forward, MI355X. Round 8 (resubmit after GPU acquisition
// timeout; no measurement happened):
//  - REVERT round-7 double-buffer (LDS 64KB halved occupancy: MfmaUtil 22.6
//    ->14%, GEMM2 95.6->152us). Back to single-buffer 2-barrier K-loop.
//  - sd fusion KEPT but via block-local LDS reduction + plain stores
//    (round-7 global atomicAdd added +25MB WRITE). m-blocks partition rows,
//    n-block == head, so each s/d element is produced by exactly one block.
//  - cvt4 merge, parallel scan, XCD-bijective remap kept (verified wins).
// ---------------------------------------------------------------------------

#define NEG_ATT 0.2f
#define NEG_ACT 0.01f

typedef __attribute__((ext_vector_type(8))) short bf16x8;
typedef __attribute__((ext_vector_type(8))) unsigned short u16x8;
typedef __attribute__((ext_vector_type(4))) float f32x4;

__device__ __forceinline__ float bf2f(unsigned short u) {
  union { unsigned int i; float f; } c; c.i = ((unsigned int)u) << 16; return c.f;
}
__device__ __forceinline__ unsigned short f2bf(float f) {
  union { float f; unsigned int i; } c; c.f = f;
  unsigned int r = c.i + 0x7FFFu + ((c.i >> 16) & 1u);
  return (unsigned short)(r >> 16);
}

// ---------------------------------------------------------------------------
// f32 -> bf16 bulk convert, 4 segments in one launch (n divisible by 8 each)
// ---------------------------------------------------------------------------
__global__ void cvt4_kernel(const float* __restrict__ i0, unsigned short* o0, int n0,
                            const float* __restrict__ i1, unsigned short* o1, int n1,
                            const float* __restrict__ i2, unsigned short* o2, int n2,
                            const float* __restrict__ i3, unsigned short* o3, int n3) {
  int i = blockIdx.x * 256 + threadIdx.x;
  const float* in; unsigned short* out; int idx;
  if (i < n0) { in = i0; out = o0; idx = i; }
  else if (i < n0 + n1) { in = i1; out = o1; idx = i - n0; }
  else if (i < n0 + n1 + n2) { in = i2; out = o2; idx = i - n0 - n1; }
  else if (i < n0 + n1 + n2 + n3) { in = i3; out = o3; idx = i - n0 - n1 - n2; }
  else return;
  float4 v0 = reinterpret_cast<const float4*>(in)[idx * 2];
  float4 v1 = reinterpret_cast<const float4*>(in)[idx * 2 + 1];
  ushort4 q0 = make_ushort4(f2bf(v0.x), f2bf(v0.y), f2bf(v0.z), f2bf(v0.w));
  ushort4 q1 = make_ushort4(f2bf(v1.x), f2bf(v1.y), f2bf(v1.z), f2bf(v1.w));
  reinterpret_cast<ushort4*>(out)[idx * 2] = q0;
  reinterpret_cast<ushort4*>(out)[idx * 2 + 1] = q1;
}

// ---------------------------------------------------------------------------
// Qb[16][256] bf16: rows 0..3 = W1_h^T a_src,h ; rows 4..7 = W1_h^T a_dst,h ;
// rows 8..15 zero (MFMA N-pad).
// ---------------------------------------------------------------------------
__global__ __launch_bounds__(256) void qb_kernel(const float* __restrict__ W1,
    const float* __restrict__ as1, const float* __restrict__ ad1,
    unsigned short* __restrict__ Qb) {
  int r = blockIdx.x;          // output row
  int k = threadIdx.x;         // 0..255
  if (r >= 8) { Qb[r * 256 + k] = 0; return; }
  int h = r & 3;
  const float* av = (r >> 2) ? ad1 : as1;
  float acc = 0.f;
#pragma unroll 8
  for (int c = 0; c < 256; c++)
    acc += W1[((size_t)(h * 256 + c)) * 256 + k] * av[h * 256 + c];
  Qb[r * 256 + k] = f2bf(acc);
}

// ---------------------------------------------------------------------------
// CSR build: histogram -> parallel 3-kernel exclusive scan -> scatter
// ---------------------------------------------------------------------------
__global__ void hist_kernel(const int* __restrict__ edge_dst,
                            int* __restrict__ cnt, int E, int N) {
  int e = blockIdx.x * 256 + threadIdx.x;
  if (e >= E + N) return;
  int dn = (e < E) ? edge_dst[e] : (e - E);   // self-loops appended
  atomicAdd(&cnt[dn], 1);
}

__global__ __launch_bounds__(256) void scan1_kernel(
    const int* __restrict__ cnt, int* __restrict__ bsum, int N) {
  __shared__ int sd_[256];
  int i = blockIdx.x * 256 + threadIdx.x;
  int v = (i < N) ? cnt[i] : 0;
  sd_[threadIdx.x] = v;
  __syncthreads();
#pragma unroll
  for (int off = 128; off; off >>= 1) {
    if (threadIdx.x < off) sd_[threadIdx.x] += sd_[threadIdx.x + off];
    __syncthreads();
  }
  if (threadIdx.x == 0) bsum[blockIdx.x] = sd_[0];
}

__global__ __launch_bounds__(256) void scan2_kernel(
    const int* __restrict__ bsum, int* __restrict__ boff,
    int* __restrict__ row_ptr, int NB, int N) {
  __shared__ int sd_[256];
  int t = threadIdx.x;
  int v = (t < NB) ? bsum[t] : 0;
  sd_[t] = v;
  __syncthreads();
#pragma unroll
  for (int off = 1; off < 256; off <<= 1) {
    int u = (t >= off) ? sd_[t - off] : 0;
    __syncthreads();
    sd_[t] += u;
    __syncthreads();
  }
  if (t < NB) boff[t] = sd_[t] - v;          // exclusive
  if (t == 255) row_ptr[N] = sd_[255];       // total
}

__global__ __launch_bounds__(256) void scan3_kernel(
    const int* __restrict__ cnt, const int* __restrict__ boff,
    int* __restrict__ row_ptr, int* __restrict__ cur, int N) {
  __shared__ int sd_[256];
  int t = threadIdx.x;
  int i = blockIdx.x * 256 + t;
  int v = (i < N) ? cnt[i] : 0;
  sd_[t] = v;
  __syncthreads();
#pragma unroll
  for (int off = 1; off < 256; off <<= 1) {
    int u = (t >= off) ? sd_[t - off] : 0;
    __syncthreads();
    sd_[t] += u;
    __syncthreads();
  }
  if (i < N) {
    int val = boff[blockIdx.x] + sd_[t] - v;
    row_ptr[i] = val;
    cur[i] = val;
  }
}

__global__ void scatter_kernel(const int* __restrict__ edge_src,
                               const int* __restrict__ edge_dst,
                               int* __restrict__ cur,
                               int* __restrict__ src_sorted, int E, int N) {
  int e = blockIdx.x * 256 + threadIdx.x;
  if (e >= E + N) return;
  int sn, dn;
  if (e < E) { sn = edge_src[e]; dn = edge_dst[e]; }
  else       { sn = dn = e - E; }
  int pos = atomicAdd(&cur[dn], 1);
  src_sorted[pos] = sn;
}

// ---------------------------------------------------------------------------
// MFMA bf16 GEMM, single-buffer 2-barrier K-loop (round-5 proven structure),
// XCD-bijective remap (m204), optional fused s/d dots via block-local LDS
// reduction + plain stores (no atomics; m-blocks partition rows, n-block ==
// head so each s/d element is produced by exactly one block).
// ---------------------------------------------------------------------------
#define GLOBAL_AS __attribute__((address_space(1)))
#define LDS_AS __attribute__((address_space(3)))

__device__ __forceinline__ void gload_lds16(const void* g, void* l) {
  __builtin_amdgcn_global_load_lds((const GLOBAL_AS unsigned int*)g,
                                   (LDS_AS unsigned int*)l, 16, 0, 0);
}

template <int BM, int BN, int WM, int WN, bool F32OUT, bool SDMODE>
__global__ __launch_bounds__(256) void gemm_mfma(
    const unsigned short* __restrict__ A, const unsigned short* __restrict__ B,
    void* __restrict__ Cv, const float* __restrict__ bias,
    int M, int N, int K, int lda, int ldb, int ldc,
    long long aZ, long long bZ, long long cZ, int biasZ,
    float* __restrict__ sOut, float* __restrict__ dOut,
    const float* __restrict__ a_s, const float* __restrict__ a_d, int H) {
  constexpr int BK = 64;
  constexpr int FM = BM / (WM * 16);
  constexpr int FN = BN / (WN * 16);
  // ---- XCD-bijective remap (m204) ----
  const int flat = blockIdx.x + gridDim.x * (blockIdx.y + gridDim.y * blockIdx.z);
  const int nwg = gridDim.x * gridDim.y * gridDim.z;
  const int xcd = flat & 7, slot = flat >> 3;
  const int q = nwg >> 3, r = nwg & 7;
  const int wgid = (xcd < r ? xcd * (q + 1) : r * (q + 1) + (xcd - r) * q) + slot;
  const int nx = gridDim.x;
  const int per_z = nx * gridDim.y;
  const int bz = wgid / per_z;
  const int rem = wgid - bz * per_z;
  const int bmi = rem / nx;
  const int bni = rem - bmi * nx;

  A += (size_t)bz * aZ;
  B += (size_t)bz * bZ;
  const size_t cbase = (size_t)bz * cZ;
  __shared__ unsigned short As[BM * BK];
  __shared__ unsigned short Bs[BN * BK];
  const int tid = threadIdx.x;
  const int w = tid >> 6, lane = tid & 63;
  const int wm = w / WN, wn = w % WN;
  const int bm = bmi * BM;
  const int bn = bni * BN;
  const int l15 = lane & 15, l4 = lane >> 4;

  f32x4 acc[FM][FN] = {};

  constexpr int CHA = BM * BK / 8;   // 16B chunks in A tile
  constexpr int CHB = BN * BK / 8;

  for (int k0 = 0; k0 < K; k0 += BK) {
#pragma unroll
    for (int c0 = 0; c0 < CHA; c0 += 256) {
      int c = c0 + tid;
      if (CHA - c0 >= 256 || tid < CHA - c0) {
        int cl = c ^ ((c >> 3) & 7);
        int row = cl >> 3;
        int kk = (cl & 7) * 8;
        int gr = bm + row; if (gr > M - 1) gr = M - 1;
        gload_lds16(A + (size_t)gr * lda + k0 + kk,
                    As + (size_t)(c0 + (tid & ~63)) * 8);
      }
    }
#pragma unroll
    for (int c0 = 0; c0 < CHB; c0 += 256) {
      int c = c0 + tid;
      if (CHB - c0 >= 256 || tid < CHB - c0) {
        int cl = c ^ ((c >> 3) & 7);
        int row = cl >> 3;
        int kk = (cl & 7) * 8;
        gload_lds16(B + (size_t)(bn + row) * ldb + k0 + kk,
                    Bs + (size_t)(c0 + (tid & ~63)) * 8);
      }
    }
    __syncthreads();
#pragma unroll
    for (int ks = 0; ks < 2; ks++) {
      bf16x8 af[FM], bfr[FN];
#pragma unroll
      for (int i = 0; i < FM; i++) {
        int row = wm * (FM * 16) + i * 16 + l15;
        int byte = row * (BK * 2) + ks * 64 + l4 * 16;
        byte ^= ((byte >> 7) & 7) << 4;
        af[i] = *reinterpret_cast<const bf16x8*>((const char*)As + byte);
      }
#pragma unroll
      for (int i = 0; i < FN; i++) {
        int row = wn * (FN * 16) + i * 16 + l15;
        int byte = row * (BK * 2) + ks * 64 + l4 * 16;
        byte ^= ((byte >> 7) & 7) << 4;
        bfr[i] = *reinterpret_cast<const bf16x8*>((const char*)Bs + byte);
      }
#pragma unroll
      for (int i = 0; i < FM; i++)
#pragma unroll
        for (int jn = 0; jn < FN; jn++)
          acc[i][jn] = __builtin_amdgcn_mfma_f32_16x16x32_bf16(
              af[i], bfr[jn], acc[i][jn], 0, 0, 0);
    }
    __syncthreads();
  }
  // ---- fused s/d dots (from f32 acc, pre-bias): per-wn LDS partials,
  //      cross-wave combine, plain global stores ----
  if constexpr (SDMODE) {
    __shared__ float sdl[WN][BM][2];
    float aws[FN], awd[FN];
#pragma unroll
    for (int jn = 0; jn < FN; jn++) {
      int c = wn * (FN * 16) + jn * 16 + l15;
      aws[jn] = a_s[bni * BN + c];
      awd[jn] = a_d[bni * BN + c];
    }
#pragma unroll
    for (int i = 0; i < FM; i++) {
#pragma unroll
      for (int r2 = 0; r2 < 4; r2++) {
        float ps = 0.f, pd = 0.f;
#pragma unroll
        for (int jn = 0; jn < FN; jn++) {
          ps = fmaf(acc[i][jn][r2], aws[jn], ps);
          pd = fmaf(acc[i][jn][r2], awd[jn], pd);
        }
#pragma unroll
        for (int o = 1; o < 16; o <<= 1) {
          ps += __shfl_xor(ps, o);
          pd += __shfl_xor(pd, o);
        }
        if (l15 == 0) {
          int rl = wm * (FM * 16) + i * 16 + l4 * 4 + r2;
          sdl[wn][rl][0] = ps;
          sdl[wn][rl][1] = pd;
        }
      }
    }
    __syncthreads();
    if (tid < BM) {
      int m = bm + tid;
      if (m < M) {
        float ss = 0.f, dd = 0.f;
#pragma unroll
        for (int j = 0; j < WN; j++) { ss += sdl[j][tid][0]; dd += sdl[j][tid][1]; }
        sOut[(size_t)m * H + bni] = ss;
        dOut[(size_t)m * H + bni] = dd;
      }
    }
  }
  // ---- C write: D col = lane&15, row = (lane>>4)*4 + reg (HW-verified) ----
#pragma unroll
  for (int i = 0; i < FM; i++) {
#pragma unroll
    for (int jn = 0; jn < FN; jn++) {
      int col = bn + wn * (FN * 16) + jn * 16 + l15;
      float bv = bias ? bias[biasZ * bz + col] : 0.f;
#pragma unroll
      for (int r2 = 0; r2 < 4; r2++) {
        int m = bm + wm * (FM * 16) + i * 16 + l4 * 4 + r2;
        if (m < M) {
          float val = acc[i][jn][r2] + bv;
          if constexpr (F32OUT)
            ((float*)Cv)[cbase + (size_t)m * ldc + col] = val;
          else
            ((unsigned short*)Cv)[cbase + (size_t)m * ldc + col] = f2bf(val);
        }
      }
    }
  }
}

// ---------------------------------------------------------------------------
// Layer-1 fused softmax + INPUT-space aggregation.
// sd1[n][0..3]=s heads, [4..7]=d heads (f32, from the Qb GEMM).
// One wave per node (4 nodes/block). 3 passes over edges: max, den, acc.
// ---------------------------------------------------------------------------
__global__ __launch_bounds__(256) void aggx_kernel(
    const int* __restrict__ row_ptr, const int* __restrict__ src_sorted,
    const float* __restrict__ sd1, const unsigned short* __restrict__ xb,
    unsigned short* __restrict__ y, int N) {
  __shared__ float alds[4][2][64][4];
  int w = threadIdx.x >> 6, lane = threadIdx.x & 63;
  int n = blockIdx.x * 4 + w;
  if (n >= N) return;
  int beg = row_ptr[n], end = row_ptr[n + 1];
  float4 dv = *reinterpret_cast<const float4*>(sd1 + (size_t)n * 16 + 4);

  auto compE = [&](int t, float e[4]) {
    if (t < end) {
      int sj = src_sorted[t];
      float4 sv = *reinterpret_cast<const float4*>(sd1 + (size_t)sj * 16);
      e[0] = sv.x + dv.x; e[1] = sv.y + dv.y;
      e[2] = sv.z + dv.z; e[3] = sv.w + dv.w;
#pragma unroll
      for (int h = 0; h < 4; h++) e[h] = e[h] > 0.f ? e[h] : NEG_ATT * e[h];
    } else {
      e[0] = e[1] = e[2] = e[3] = -1e30f;
    }
  };

  float mx[4] = {-1e30f, -1e30f, -1e30f, -1e30f};
  for (int cb = beg; cb < end; cb += 64) {
    float e[4]; compE(cb + lane, e);
#pragma unroll
    for (int h = 0; h < 4; h++) {
      float m = e[h];
#pragma unroll
      for (int o = 32; o; o >>= 1) m = fmaxf(m, __shfl_xor(m, o));
      mx[h] = fmaxf(mx[h], m);
    }
  }
  float den[4] = {0.f, 0.f, 0.f, 0.f};
  for (int cb = beg; cb < end; cb += 64) {
    float e[4]; compE(cb + lane, e);
#pragma unroll
    for (int h = 0; h < 4; h++) {
      float p = __expf(e[h] - mx[h]);
#pragma unroll
      for (int o = 32; o; o >>= 1) p += __shfl_xor(p, o);
      den[h] += p;
    }
  }
  float ia[4];
#pragma unroll
  for (int h = 0; h < 4; h++) ia[h] = 1.0f / (den[h] + 1e-16f);

  float acc[4][4] = {};
  for (int cb = beg; cb < end; cb += 64) {
    float e[4]; compE(cb + lane, e);
    int pb = ((cb - beg) >> 6) & 1;
    float4 al;
    al.x = __expf(e[0] - mx[0]) * ia[0];
    al.y = __expf(e[1] - mx[1]) * ia[1];
    al.z = __expf(e[2] - mx[2]) * ia[2];
    al.w = __expf(e[3] - mx[3]) * ia[3];
    *reinterpret_cast<float4*>(alds[w][pb][lane]) = al;
    int cd = end - cb; if (cd > 64) cd = 64;
    for (int j = 0; j < cd; j++) {
      float4 a4 = *reinterpret_cast<const float4*>(alds[w][pb][j]);
      int sj = src_sorted[cb + j];
      ushort4 xv = *reinterpret_cast<const ushort4*>(
          xb + (size_t)sj * 256 + lane * 4);
      float x0 = bf2f(xv.x), x1 = bf2f(xv.y), x2 = bf2f(xv.z), x3 = bf2f(xv.w);
      float ar[4] = {a4.x, a4.y, a4.z, a4.w};
#pragma unroll
      for (int h = 0; h < 4; h++) {
        acc[h][0] = fmaf(ar[h], x0, acc[h][0]);
        acc[h][1] = fmaf(ar[h], x1, acc[h][1]);
        acc[h][2] = fmaf(ar[h], x2, acc[h][2]);
        acc[h][3] = fmaf(ar[h], x3, acc[h][3]);
      }
    }
  }
#pragma unroll
  for (int h = 0; h < 4; h++) {
    ushort4 o = make_ushort4(f2bf(acc[h][0]), f2bf(acc[h][1]),
                             f2bf(acc[h][2]), f2bf(acc[h][3]));
    *reinterpret_cast<ushort4*>(y + (size_t)n * 1024 + h * 256 + lane * 4) = o;
  }
}

// ---------------------------------------------------------------------------
// Layer-2 fused softmax + aggregation + bias + LN(512) + leaky_relu.
// ---------------------------------------------------------------------------
__global__ __launch_bounds__(256) void agg2m_kernel(
    const int* __restrict__ row_ptr, const int* __restrict__ src_sorted,
    const float* __restrict__ s2, const float* __restrict__ d2,
    const unsigned short* __restrict__ h2, const float* __restrict__ bias,
    const float* __restrict__ ln_g, const float* __restrict__ ln_b,
    unsigned short* __restrict__ outb, int N) {
  __shared__ float alds[4][2][64][4];
  int w = threadIdx.x >> 6, lane = threadIdx.x & 63;
  int n = blockIdx.x * 4 + w;
  if (n >= N) return;
  int beg = row_ptr[n], end = row_ptr[n + 1];
  int head = lane >> 4, c0 = lane * 8;
  float4 dv = *reinterpret_cast<const float4*>(d2 + (size_t)n * 4);

  auto compE = [&](int t, float e[4]) {
    if (t < end) {
      int sj = src_sorted[t];
      float4 sv = *reinterpret_cast<const float4*>(s2 + (size_t)sj * 4);
      e[0] = sv.x + dv.x; e[1] = sv.y + dv.y;
      e[2] = sv.z + dv.z; e[3] = sv.w + dv.w;
#pragma unroll
      for (int h = 0; h < 4; h++) e[h] = e[h] > 0.f ? e[h] : NEG_ATT * e[h];
    } else {
      e[0] = e[1] = e[2] = e[3] = -1e30f;
    }
  };

  float mx[4] = {-1e30f, -1e30f, -1e30f, -1e30f};
  for (int cb = beg; cb < end; cb += 64) {
    float e[4]; compE(cb + lane, e);
#pragma unroll
    for (int h = 0; h < 4; h++) {
      float m = e[h];
#pragma unroll
      for (int o = 32; o; o >>= 1) m = fmaxf(m, __shfl_xor(m, o));
      mx[h] = fmaxf(mx[h], m);
    }
  }
  float den[4] = {0.f, 0.f, 0.f, 0.f};
  for (int cb = beg; cb < end; cb += 64) {
    float e[4]; compE(cb + lane, e);
#pragma unroll
    for (int h = 0; h < 4; h++) {
      float p = __expf(e[h] - mx[h]);
#pragma unroll
      for (int o = 32; o; o >>= 1) p += __shfl_xor(p, o);
      den[h] += p;
    }
  }
  float ia[4];
#pragma unroll
  for (int h = 0; h < 4; h++) ia[h] = 1.0f / (den[h] + 1e-16f);

  float acc[8] = {};
  for (int cb = beg; cb < end; cb += 64) {
    float e[4]; compE(cb + lane, e);
    int pb = ((cb - beg) >> 6) & 1;
    float4 al;
    al.x = __expf(e[0] - mx[0]) * ia[0];
    al.y = __expf(e[1] - mx[1]) * ia[1];
    al.z = __expf(e[2] - mx[2]) * ia[2];
    al.w = __expf(e[3] - mx[3]) * ia[3];
    *reinterpret_cast<float4*>(alds[w][pb][lane]) = al;
    int cd = end - cb; if (cd > 64) cd = 64;
    for (int j = 0; j < cd; j++) {
      float a = alds[w][pb][j][head];
      int sj = src_sorted[cb + j];
      u16x8 xv = *reinterpret_cast<const u16x8*>(h2 + (size_t)sj * 512 + c0);
#pragma unroll
      for (int i = 0; i < 8; i++)
        acc[i] = fmaf(a, bf2f(xv[i]), acc[i]);
    }
  }
  float v[8], s1 = 0.f, sq = 0.f;
#pragma unroll
  for (int i = 0; i < 8; i++) {
    v[i] = acc[i] + bias[c0 + i];
    s1 += v[i]; sq += v[i] * v[i];
  }
#pragma unroll
  for (int o = 32; o; o >>= 1) { s1 += __shfl_xor(s1, o); sq += __shfl_xor(sq, o); }
  float mean = s1 * (1.0f / 512.0f);
  float var = sq * (1.0f / 512.0f) - mean * mean;
  float rstd = rsqrtf(var + 1e-5f);
  u16x8 ov;
#pragma unroll
  for (int i = 0; i < 8; i++) {
    float yv = (v[i] - mean) * rstd * ln_g[c0 + i] + ln_b[c0 + i];
    yv = yv > 0.f ? yv : NEG_ACT * yv;
    ov[i] = f2bf(yv);
  }
  *reinterpret_cast<u16x8*>(outb + (size_t)n * 512 + c0) = ov;
}

// ---------------------------------------------------------------------------
// LN(1024) + leaky over z1 -> act1 (bias folded into GEMM epilogue).
// ---------------------------------------------------------------------------
__global__ __launch_bounds__(256) void ln1024_kernel(
    const unsigned short* __restrict__ z, const float* __restrict__ ln_g,
    const float* __restrict__ ln_b, unsigned short* __restrict__ outb, int N) {
  int n = blockIdx.x;
  int tid = threadIdx.x;
  int c0 = tid * 4;
  ushort4 zv = *reinterpret_cast<const ushort4*>(z + (size_t)n * 1024 + c0);
  float v[4] = {bf2f(zv.x), bf2f(zv.y), bf2f(zv.z), bf2f(zv.w)};
  float s1 = v[0] + v[1] + v[2] + v[3];
  float sq = v[0]*v[0] + v[1]*v[1] + v[2]*v[2] + v[3]*v[3];
#pragma unroll
  for (int o = 32; o; o >>= 1) { s1 += __shfl_down(s1, o); sq += __shfl_down(sq, o); }
  __shared__ float r1[4], r2[4];
  int wave = tid >> 6, lane = tid & 63;
  if (lane == 0) { r1[wave] = s1; r2[wave] = sq; }
  __syncthreads();
  float t1 = r1[0] + r1[1] + r1[2] + r1[3];
  float t2 = r2[0] + r2[1] + r2[2] + r2[3];
  float mean = t1 * (1.0f / 1024.0f);
  float var = t2 * (1.0f / 1024.0f) - mean * mean;
  float rstd = rsqrtf(var + 1e-5f);
  ushort4 ov;
  float y0 = (v[0] - mean) * rstd * ln_g[c0 + 0] + ln_b[c0 + 0];
  float y1 = (v[1] - mean) * rstd * ln_g[c0 + 1] + ln_b[c0 + 1];
  float y2 = (v[2] - mean) * rstd * ln_g[c0 + 2] + ln_b[c0 + 2];
  float y3 = (v[3] - mean) * rstd * ln_g[c0 + 3] + ln_b[c0 + 3];
  ov.x = f2bf(y0 > 0.f ? y0 : NEG_ACT * y0);
  ov.y = f2bf(y1 > 0.f ? y1 : NEG_ACT * y1);
  ov.z = f2bf(y2 > 0.f ? y2 : NEG_ACT * y2);
  ov.w = f2bf(y3 > 0.f ? y3 : NEG_ACT * y3);
  *reinterpret_cast<ushort4*>(outb + (size_t)n * 1024 + c0) = ov;
}

// ---------------------------------------------------------------------------
// Layer-3 softmax stats (H=1).
// ---------------------------------------------------------------------------
__global__ void stats_kernel(const int* __restrict__ row_ptr,
    const int* __restrict__ src_sorted, const float* __restrict__ s,
    const float* __restrict__ d, float* __restrict__ p_sorted,
    float* __restrict__ inv_den, int N) {
  int idx = blockIdx.x * blockDim.x + threadIdx.x;
  if (idx >= N) return;
  int n = idx;
  int beg = row_ptr[n], end = row_ptr[n + 1];
  float dn = d[n];
  float mx = -1e30f;
  for (int j = beg; j < end; j++) {
    float v = s[src_sorted[j]] + dn;
    v = v > 0.f ? v : NEG_ATT * v;
    mx = fmaxf(mx, v);
  }
  float den = 0.f;
  for (int j = beg; j < end; j++) {
    float v = s[src_sorted[j]] + dn;
    v = v > 0.f ? v : NEG_ATT * v;
    float p = __expf(v - mx);
    p_sorted[j] = p;
    den += p;
  }
  inv_den[n] = 1.0f / (den + 1e-16f);
}

// ---------------------------------------------------------------------------
// Layer-3 aggregation + bias + LN(32) + log_softmax(32) -> f32 output.
// ---------------------------------------------------------------------------
__global__ __launch_bounds__(256) void final_kernel(
    const int* __restrict__ row_ptr, const int* __restrict__ src_sorted,
    const float* __restrict__ p_sorted, const float* __restrict__ inv_den,
    const unsigned short* __restrict__ h3, const float* __restrict__ b3,
    const float* __restrict__ g3, const float* __restrict__ bb3,
    float* __restrict__ out, int N) {
  int idx = blockIdx.x * 256 + threadIdx.x;
  int n = idx >> 5, c = idx & 31;
  if (n >= N) return;
  int beg = row_ptr[n], end = row_ptr[n + 1];
  float acc = 0.f;
  for (int j = beg; j < end; j++)
    acc = fmaf(p_sorted[j], bf2f(h3[(size_t)src_sorted[j] * 32 + c]), acc);
  float v = acc * inv_den[n] + b3[c];
  float s1 = v, s2 = v * v;
#pragma unroll
  for (int o = 16; o; o >>= 1) { s1 += __shfl_xor(s1, o, 32); s2 += __shfl_xor(s2, o, 32); }
  float mean = s1 * (1.f / 32.f), var = s2 * (1.f / 32.f) - mean * mean;
  float y = (v - mean) * rsqrtf(var + 1e-5f) * g3[c] + bb3[c];
  float mx = y;
#pragma unroll
  for (int o = 16; o; o >>= 1) mx = fmaxf(mx, __shfl_xor(mx, o, 32));
  float ex = __expf(y - mx), se = ex;
#pragma unroll
  for (int o = 16; o; o >>= 1) se += __shfl_xor(se, o, 32);
  out[(size_t)n * 32 + c] = y - mx - __logf(se);
}

// ---------------------------------------------------------------------------
extern "C" void kernel_launch(void* const* d_in, const int* in_sizes, int n_in,
                              void* d_out, int out_size, void* d_ws,
                              size_t ws_size, hipStream_t stream) {
  const float* x   = (const float*)d_in[0];
  const int* esrc  = (const int*)d_in[1];
  const int* edst  = (const int*)d_in[2];
  const float* W1  = (const float*)d_in[3];
  const float* as1 = (const float*)d_in[4];
  const float* ad1 = (const float*)d_in[5];
  const float* b1  = (const float*)d_in[6];
  const float* g1  = (const float*)d_in[7];
  const float* bb1 = (const float*)d_in[8];
  const float* W2  = (const float*)d_in[9];
  const float* as2 = (const float*)d_in[10];
  const float* ad2 = (const float*)d_in[11];
  const float* b2  = (const float*)d_in[12];
  const float* g2  = (const float*)d_in[13];
  const float* bb2 = (const float*)d_in[14];
  const float* W3  = (const float*)d_in[15];
  const float* as3 = (const float*)d_in[16];
  const float* ad3 = (const float*)d_in[17];
  const float* b3  = (const float*)d_in[18];
  const float* g3  = (const float*)d_in[19];
  const float* bb3 = (const float*)d_in[20];
  float* out = (float*)d_out;

  const int Nn = in_sizes[0] / 256;  // 50000
  const int E  = in_sizes[1];        // 400000
  const int Etot = E + Nn;
  const int NB = (Nn + 255) / 256;   // 196 scan blocks (<=256 required)

  char* ws = (char*)d_ws;
  size_t off = 0;
  auto alloc = [&](size_t bytes) -> char* {
    char* p = ws + off;
    off += (bytes + 255) & ~(size_t)255;
    return p;
  };
  // small buffers
  int* cnt        = (int*)alloc((size_t)(Nn + 1) * 4);
  int* cur        = (int*)alloc((size_t)(Nn + 1) * 4);
  int* row_ptr    = (int*)alloc((size_t)(Nn + 1) * 4);
  int* bsum       = (int*)alloc(256 * 4);
  int* boff       = (int*)alloc(256 * 4);
  int* src_sorted = (int*)alloc((size_t)Etot * 4);
  float* sd1   = (float*)alloc((size_t)Nn * 16 * 4);   // s(0..3), d(4..7)
  float* s2    = (float*)alloc((size_t)Nn * 4 * 4);
  float* d2    = (float*)alloc((size_t)Nn * 4 * 4);
  float* s3    = (float*)alloc((size_t)Nn * 4);
  float* d3    = (float*)alloc((size_t)Nn * 4);
  float* invd3 = (float*)alloc((size_t)Nn * 4);
  float* p3    = (float*)alloc((size_t)Etot * 4);
  unsigned short* W1b = (unsigned short*)alloc((size_t)1024 * 256 * 2);
  unsigned short* W2b = (unsigned short*)alloc((size_t)512 * 1024 * 2);
  unsigned short* W3b = (unsigned short*)alloc((size_t)32 * 512 * 2);
  unsigned short* Qb  = (unsigned short*)alloc((size_t)16 * 256 * 2);
  unsigned short* h3  = (unsigned short*)alloc((size_t)Nn * 32 * 2);
  // big regions (102.4 MB each) with lifetime-based overlays:
  //   regionA: y -> act1 -> act2
  //   regionB: xb -> z1 -> h2
  unsigned short* regA = (unsigned short*)alloc((size_t)Nn * 1024 * 2);
  unsigned short* regB = (unsigned short*)alloc((size_t)Nn * 1024 * 2);
  unsigned short* y    = regA;
  unsigned short* act1 = regA;
  unsigned short* act2 = regA;
  unsigned short* xb   = regB;
  unsigned short* z1   = regB;
  unsigned short* h2   = regB;

  const int mb = (Nn + 127) / 128;

  // ---- prep: bf16 conversions (single launch) + Qb ----
  {
    int n0 = Nn * 256 / 8, n1 = 1024 * 256 / 8, n2 = 512 * 1024 / 8, n3 = 32 * 512 / 8;
    int tot = n0 + n1 + n2 + n3;
    cvt4_kernel<<<(tot + 255) / 256, 256, 0, stream>>>(
        x, xb, n0, W1, W1b, n1, W2, W2b, n2, W3, W3b, n3);
  }
  qb_kernel<<<16, 256, 0, stream>>>(W1, as1, ad1, Qb);

  // ---- CSR by dst (parallel scan) ----
  hipMemsetAsync(cnt, 0, (size_t)(Nn + 1) * 4, stream);
  int eb = (Etot + 255) / 256;
  hist_kernel<<<eb, 256, 0, stream>>>(edst, cnt, E, Nn);
  scan1_kernel<<<NB, 256, 0, stream>>>(cnt, bsum, Nn);
  scan2_kernel<<<1, 256, 0, stream>>>(bsum, boff, row_ptr, NB, Nn);
  scan3_kernel<<<NB, 256, 0, stream>>>(cnt, boff, row_ptr, cur, Nn);
  scatter_kernel<<<eb, 256, 0, stream>>>(esrc, edst, cur, src_sorted, E, Nn);

  // ---- layer 1 (input-space aggregation) ----
  gemm_mfma<128, 16, 4, 1, true, false><<<dim3(1, mb, 1), 256, 0, stream>>>(
      xb, Qb, sd1, nullptr, Nn, 16, 256, 256, 256, 16, 0, 0, 0, 0,
      nullptr, nullptr, nullptr, nullptr, 0);
  aggx_kernel<<<(Nn + 3) / 4, 256, 0, stream>>>(row_ptr, src_sorted, sd1, xb, y, Nn);
  gemm_mfma<128, 128, 2, 2, false, false><<<dim3(2, mb, 4), 256, 0, stream>>>(
      y, W1b, z1, b1, Nn, 256, 256, 1024, 256, 1024, 256LL, 256LL * 256, 256LL, 256,
      nullptr, nullptr, nullptr, nullptr, 0);
  ln1024_kernel<<<Nn, 256, 0, stream>>>(z1, g1, bb1, act1, Nn);

  // ---- layer 2 (sd fused into GEMM epilogue, LDS-reduced) ----
  gemm_mfma<128, 128, 2, 2, false, true><<<dim3(4, mb, 1), 256, 0, stream>>>(
      act1, W2b, h2, nullptr, Nn, 512, 1024, 1024, 1024, 512, 0, 0, 0, 0,
      s2, d2, as2, ad2, 4);
  agg2m_kernel<<<(Nn + 3) / 4, 256, 0, stream>>>(row_ptr, src_sorted, s2, d2,
                                                 h2, b2, g2, bb2, act2, Nn);

  // ---- layer 3 (sd fused into GEMM epilogue, LDS-reduced) ----
  gemm_mfma<128, 32, 4, 1, false, true><<<dim3(1, mb, 1), 256, 0, stream>>>(
      act2, W3b, h3, nullptr, Nn, 32, 512, 512, 512, 32, 0, 0, 0, 0,
      s3, d3, as3, ad3, 1);
  stats_kernel<<<(Nn + 255) / 256, 256, 0, stream>>>(row_ptr, src_sorted,
                                                     s3, d3, p3, invd3, Nn);
  final_kernel<<<(Nn * 32 + 255) / 256, 256, 0, stream>>>(row_ptr, src_sorted,
      p3, invd3, h3, b3, g3, bb3, out, Nn);
}